// Round 1
// baseline (514.594 us; speedup 1.0000x reference)
//
#include <hip/hip_runtime.h>
#include <math.h>

#define B 16
#define C 256
#define H 4
#define D 32
#define HID 128
#define O3 384
#define N 4096
#define QSCALE 0.17677669529663687f  // 1/sqrt(32)
#define RMS_MUL 16.0f                // sqrt(256)
#define EPS 1e-12f

// ---- per-pixel inverse norm over 256 channels (used for both rmsnorms) ----
__global__ __launch_bounds__(256) void k_invnorm(const float* __restrict__ src,
                                                 float* __restrict__ invn) {
  int p = blockIdx.x * 256 + threadIdx.x;   // p in [0, B*N)
  int b = p >> 12, n = p & (N - 1);
  const float* base = src + (size_t)b * C * N + n;
  float s = 0.f;
  for (int c = 0; c < C; ++c) { float v = base[(size_t)c * N]; s += v * v; }
  invn[p] = RMS_MUL / fmaxf(sqrtf(s), EPS);
}

// ---- QKV GEMM: qkv[b,o,n] = invn[b,n] * sum_c (W[o,c]*g[c]) * x[b,c,n] ----
__global__ __launch_bounds__(256) void k_qkv(const float* __restrict__ x,
                                             const float* __restrict__ wqkv,
                                             const float* __restrict__ g,
                                             const float* __restrict__ invn,
                                             float* __restrict__ qkv) {
  __shared__ float wl[C * 16];
  int t = threadIdx.x;
  int n = blockIdx.x * 256 + t;
  int o0 = blockIdx.y * 16;
  int b = blockIdx.z;
  float gc = g[t];                     // t == c here (C == 256 == blockDim)
  #pragma unroll
  for (int ii = 0; ii < 16; ++ii) wl[t * 16 + ii] = wqkv[(o0 + ii) * C + t] * gc;
  __syncthreads();
  float acc[16];
  #pragma unroll
  for (int i = 0; i < 16; ++i) acc[i] = 0.f;
  const float* xb = x + (size_t)b * C * N + n;
  for (int c = 0; c < C; ++c) {
    float xv = xb[(size_t)c * N];
    #pragma unroll
    for (int i = 0; i < 16; ++i) acc[i] += wl[c * 16 + i] * xv;
  }
  float inv = invn[b * N + n];
  float* ob = qkv + ((size_t)b * O3 + o0) * N + n;
  #pragma unroll
  for (int i = 0; i < 16; ++i) ob[(size_t)i * N] = acc[i] * inv;
}

// ---- q softmax over D=32 (axis=-2), scale folded in; in place ----
__global__ __launch_bounds__(256) void k_qsoftmax(float* __restrict__ qkv) {
  int idx = blockIdx.x * 256 + threadIdx.x;   // B*H*N threads
  int n = idx & (N - 1);
  int bh = idx >> 12;
  int b = bh >> 2, h = bh & 3;
  float* base = qkv + ((size_t)b * O3 + h * D) * N + n;
  float v[D];
  float m = -1e30f;
  #pragma unroll
  for (int d = 0; d < D; ++d) { v[d] = base[(size_t)d * N]; m = fmaxf(m, v[d]); }
  float s = 0.f;
  #pragma unroll
  for (int d = 0; d < D; ++d) { v[d] = expf(v[d] - m); s += v[d]; }
  float rs = QSCALE / s;
  #pragma unroll
  for (int d = 0; d < D; ++d) base[(size_t)d * N] = v[d] * rs;
}

// ---- k softmax over N=4096 (axis=-1); one block per row; in place ----
__global__ __launch_bounds__(256) void k_ksoftmax(float* __restrict__ qkv) {
  __shared__ float red[4];
  int r = blockIdx.x;                 // B*H*D = 2048 rows
  int b = r >> 7, rem = r & 127;
  float* row = qkv + ((size_t)b * O3 + HID + rem) * N;
  int t = threadIdx.x;
  float v[16];
  float m = -1e30f;
  #pragma unroll
  for (int i = 0; i < 16; ++i) { v[i] = row[i * 256 + t]; m = fmaxf(m, v[i]); }
  #pragma unroll
  for (int off = 32; off; off >>= 1) m = fmaxf(m, __shfl_xor(m, off));
  if ((t & 63) == 0) red[t >> 6] = m;
  __syncthreads();
  m = fmaxf(fmaxf(red[0], red[1]), fmaxf(red[2], red[3]));
  __syncthreads();
  float s = 0.f;
  #pragma unroll
  for (int i = 0; i < 16; ++i) { v[i] = expf(v[i] - m); s += v[i]; }
  #pragma unroll
  for (int off = 32; off; off >>= 1) s += __shfl_xor(s, off);
  if ((t & 63) == 0) red[t >> 6] = s;
  __syncthreads();
  s = red[0] + red[1] + red[2] + red[3];
  float rs = 1.f / s;
  #pragma unroll
  for (int i = 0; i < 16; ++i) row[i * 256 + t] = v[i] * rs;
}

// ---- context[b,h,d,e] = sum_n k[d,n]*v[e,n] ----
__global__ __launch_bounds__(256) void k_context(const float* __restrict__ qkv,
                                                 float* __restrict__ ctx) {
  __shared__ float kt[32 * 129];
  __shared__ float vt[32 * 129];
  int bh = blockIdx.x;                // 64 blocks
  int b = bh >> 2, h = bh & 3;
  int t = threadIdx.x;
  int d = t >> 3, e0 = (t & 7) * 4;
  float acc[4] = {0.f, 0.f, 0.f, 0.f};
  const float* kbase = qkv + ((size_t)b * O3 + HID + h * D) * N;
  const float* vbase = qkv + ((size_t)b * O3 + 2 * HID + h * D) * N;
  for (int n0 = 0; n0 < N; n0 += 128) {
    __syncthreads();
    #pragma unroll
    for (int j = 0; j < 16; ++j) {
      int f = j * 256 + t;            // 0..4095
      int row = f >> 7, col = f & 127;
      kt[row * 129 + col] = kbase[(size_t)row * N + n0 + col];
      vt[row * 129 + col] = vbase[(size_t)row * N + n0 + col];
    }
    __syncthreads();
    for (int nn = 0; nn < 128; ++nn) {
      float kd = kt[d * 129 + nn];
      #pragma unroll
      for (int j = 0; j < 4; ++j) acc[j] += kd * vt[(e0 + j) * 129 + nn];
    }
  }
  float* cb = ctx + ((size_t)bh * D + d) * D + e0;
  #pragma unroll
  for (int j = 0; j < 4; ++j) cb[j] = acc[j];
}

// ---- out2[b, h*32+e, n] = sum_d ctx[b,h,d,e] * q[b,h,d,n]  (q pre-scaled) ----
__global__ __launch_bounds__(256) void k_out2(const float* __restrict__ qkv,
                                              const float* __restrict__ ctx,
                                              float* __restrict__ out2) {
  __shared__ float cl[D * D];
  int t = threadIdx.x;
  int n = blockIdx.x * 256 + t;
  int bh = blockIdx.y;
  int b = bh >> 2, h = bh & 3;
  #pragma unroll
  for (int j = 0; j < 4; ++j) cl[j * 256 + t] = ctx[(size_t)bh * D * D + j * 256 + t];
  __syncthreads();
  float q[D];
  const float* qb = qkv + ((size_t)b * O3 + h * D) * N + n;
  #pragma unroll
  for (int d = 0; d < D; ++d) q[d] = qb[(size_t)d * N];
  float* ob = out2 + ((size_t)b * HID + h * D) * N + n;
  for (int e = 0; e < D; ++e) {
    float a = 0.f;
    #pragma unroll
    for (int d = 0; d < D; ++d) a += cl[d * D + e] * q[d];
    ob[(size_t)e * N] = a;
  }
}

// ---- final GEMM: out[b,o,n] = b_out[o] + sum_e Wout[o,e]*out2[b,e,n] ----
__global__ __launch_bounds__(256) void k_final(const float* __restrict__ out2,
                                               const float* __restrict__ wout,
                                               const float* __restrict__ bout,
                                               float* __restrict__ out) {
  __shared__ float wl[HID * 16];
  int t = threadIdx.x;
  int n = blockIdx.x * 256 + t;
  int o0 = blockIdx.y * 16;
  int b = blockIdx.z;
  #pragma unroll
  for (int j = 0; j < 8; ++j) {
    int f = j * 256 + t;              // f = e*16 + ii
    int e = f >> 4, ii = f & 15;
    wl[f] = wout[(o0 + ii) * HID + e];
  }
  __syncthreads();
  float acc[16];
  #pragma unroll
  for (int i = 0; i < 16; ++i) acc[i] = bout[o0 + i];
  const float* xb = out2 + (size_t)b * HID * N + n;
  for (int e = 0; e < HID; ++e) {
    float xv = xb[(size_t)e * N];
    #pragma unroll
    for (int i = 0; i < 16; ++i) acc[i] += wl[e * 16 + i] * xv;
  }
  float* ob = out + ((size_t)b * C + o0) * N + n;
  #pragma unroll
  for (int i = 0; i < 16; ++i) ob[(size_t)i * N] = acc[i];
}

// ---- in-place final rmsnorm scale ----
__global__ __launch_bounds__(256) void k_scale(float* __restrict__ out,
                                               const float* __restrict__ invn,
                                               const float* __restrict__ g) {
  size_t idx = (size_t)blockIdx.x * 256 + threadIdx.x;  // B*C*N
  int n = (int)(idx & (N - 1));
  int c = (int)((idx >> 12) & (C - 1));
  int b = (int)(idx >> 20);
  out[idx] *= invn[b * N + n] * g[c];
}

extern "C" void kernel_launch(void* const* d_in, const int* in_sizes, int n_in,
                              void* d_out, int out_size, void* d_ws, size_t ws_size,
                              hipStream_t stream) {
  const float* x    = (const float*)d_in[0];
  const float* gn   = (const float*)d_in[1];
  const float* wqkv = (const float*)d_in[2];
  const float* wout = (const float*)d_in[3];
  const float* bout = (const float*)d_in[4];
  const float* gout = (const float*)d_in[5];
  float* out = (float*)d_out;
  float* ws  = (float*)d_ws;

  float* qkv   = ws;                          // 25,165,824 floats
  float* out2  = ws + 25165824;               //  8,388,608 floats
  float* invn1 = ws + 33554432;               //     65,536 floats
  float* invn2 = ws + 33619968;               //     65,536 floats
  float* ctx   = ws + 33685504;               //     65,536 floats

  k_invnorm <<<256, 256, 0, stream>>>(x, invn1);
  k_qkv     <<<dim3(16, 24, 16), 256, 0, stream>>>(x, wqkv, gn, invn1, qkv);
  k_qsoftmax<<<1024, 256, 0, stream>>>(qkv);
  k_ksoftmax<<<2048, 256, 0, stream>>>(qkv);
  k_context <<<64, 256, 0, stream>>>(qkv, ctx);
  k_out2    <<<dim3(16, 64), 256, 0, stream>>>(qkv, ctx, out2);
  k_final   <<<dim3(16, 16, 16), 256, 0, stream>>>(out2, wout, bout, out);
  k_invnorm <<<256, 256, 0, stream>>>(out, invn2);
  k_scale   <<<65536, 256, 0, stream>>>(out, invn2, gout);
}

// Round 2
// 263.599 us; speedup vs baseline: 1.9522x; 1.9522x over previous
//
// R2: bf16 MFMA for both big GEMMs (m97-style 128x128 tile, global_load_lds w16),
//     fused final rmsnorm, bf16 K-major activation layouts.
#include <hip/hip_runtime.h>
#include <hip/hip_bf16.h>
#include <math.h>

#define B 16
#define C 256
#define H 4
#define D 32
#define HID 128
#define O3 384
#define N 4096
#define QSCALE 0.17677669529663687f  // 1/sqrt(32)
#define RMS_MUL 16.0f                // sqrt(256)
#define EPS 1e-12f

typedef __attribute__((ext_vector_type(8))) short short8;
typedef __attribute__((ext_vector_type(4))) float f32x4;

__device__ __forceinline__ ushort f2bf(float f) {
  __hip_bfloat16 h = __float2bfloat16(f);
  return *(ushort*)&h;
}
__device__ __forceinline__ float bf2f(ushort u) {
  unsigned int v = ((unsigned int)u) << 16;
  return *(float*)&v;
}
__device__ __forceinline__ void load_lds16(const void* g, void* l) {
  __builtin_amdgcn_global_load_lds((const __attribute__((address_space(1))) void*)g,
                                   (__attribute__((address_space(3))) void*)l, 16, 0, 0);
}

// ---- weight prep: wA[o][c] = bf16(wqkv[o][c]*g[c]); wB = bf16(wout) ----
__global__ __launch_bounds__(256) void k_prep_w(const float* __restrict__ wqkv,
                                                const float* __restrict__ g,
                                                const float* __restrict__ wout,
                                                ushort* __restrict__ wA,
                                                ushort* __restrict__ wB) {
  int idx = blockIdx.x * 256 + threadIdx.x;          // 0 .. 131071
  if (idx < O3 * C) {
    wA[idx] = f2bf(wqkv[idx] * g[idx & (C - 1)]);
  } else {
    int j = idx - O3 * C;                            // 0 .. 32767
    wB[j] = f2bf(wout[j]);
  }
}

// ---- x prep: rmsnorm + transpose to xbf[b][n][c] (bf16, c contiguous) ----
__global__ __launch_bounds__(256) void k_prep_x(const float* __restrict__ x,
                                                ushort* __restrict__ xbf) {
  __shared__ ushort xl[C][64];       // [c][n] raw bf16, 32KB
  __shared__ float red[4][64];
  __shared__ float invs[64];
  int t = threadIdx.x, w4 = t >> 6, ln = t & 63;
  int b = blockIdx.y, n0 = blockIdx.x * 64;
  const float* xb = x + (size_t)b * C * N + n0;
  float ss = 0.f;
  #pragma unroll
  for (int it = 0; it < 64; ++it) {
    int c = it * 4 + w4;
    float v = xb[(size_t)c * N + ln];
    ss += v * v;
    xl[c][ln] = f2bf(v);
  }
  red[w4][ln] = ss;
  __syncthreads();
  if (t < 64) {
    float tot = red[0][t] + red[1][t] + red[2][t] + red[3][t];
    invs[t] = RMS_MUL / fmaxf(sqrtf(tot), EPS);
  }
  __syncthreads();
  float inv = invs[ln];
  ushort* dst = xbf + ((size_t)(b * N + n0 + ln)) * C + w4 * 64;
  #pragma unroll
  for (int ch = 0; ch < 8; ++ch) {
    union { ushort s[8]; uint4 v; } u;
    #pragma unroll
    for (int j = 0; j < 8; ++j)
      u.s[j] = f2bf(bf2f(xl[w4 * 64 + ch * 8 + j][ln]) * inv);
    *(uint4*)(dst + ch * 8) = u.v;
  }
}

// ---- MFMA GEMM (C = A * B^T): A[M][K] bf16, Bm[b][4096][K] bf16, Cout[b][M][4096] f32 ----
template <int K, bool BIAS>
__global__ __launch_bounds__(256) void k_gemm(const ushort* __restrict__ A,
                                              const ushort* __restrict__ Bm,
                                              const float* __restrict__ bias,
                                              float* __restrict__ Cout, int M) {
  __shared__ ushort Abuf[128 * 64];
  __shared__ ushort Bbuf[128 * 64];
  int t = threadIdx.x;
  int lane = t & 63, w = t >> 6;
  int wr = w >> 1, wc = w & 1;
  int n0 = blockIdx.x * 128, o0 = blockIdx.y * 128, b = blockIdx.z;
  const ushort* Ab = A + (size_t)o0 * K;
  const ushort* Bb = Bm + ((size_t)b * N + n0) * K;
  f32x4 acc[4][4] = {};
  for (int k0 = 0; k0 < K; k0 += 64) {
    #pragma unroll
    for (int i = 0; i < 4; ++i) {
      int chunk = w * 4 + i;                     // 0..15
      int row = chunk * 8 + (lane >> 3);
      int col = k0 + (lane & 7) * 8;
      load_lds16(Ab + (size_t)row * K + col, Abuf + chunk * 512);
      load_lds16(Bb + (size_t)row * K + col, Bbuf + chunk * 512);
    }
    __syncthreads();                              // drains vmcnt before compute
    #pragma unroll
    for (int kk = 0; kk < 2; ++kk) {
      short8 af[4], bfr[4];
      #pragma unroll
      for (int m = 0; m < 4; ++m)
        af[m] = *(const short8*)&Abuf[(wr * 64 + m * 16 + (lane & 15)) * 64 + kk * 32 + (lane >> 4) * 8];
      #pragma unroll
      for (int nn = 0; nn < 4; ++nn)
        bfr[nn] = *(const short8*)&Bbuf[(wc * 64 + nn * 16 + (lane & 15)) * 64 + kk * 32 + (lane >> 4) * 8];
      #pragma unroll
      for (int m = 0; m < 4; ++m)
        #pragma unroll
        for (int nn = 0; nn < 4; ++nn)
          acc[m][nn] = __builtin_amdgcn_mfma_f32_16x16x32_bf16(af[m], bfr[nn], acc[m][nn], 0, 0, 0);
    }
    __syncthreads();
  }
  float* Cb = Cout + ((size_t)b * M + o0) * N + n0;
  #pragma unroll
  for (int m = 0; m < 4; ++m)
    #pragma unroll
    for (int nn = 0; nn < 4; ++nn)
      #pragma unroll
      for (int j = 0; j < 4; ++j) {
        int row = wr * 64 + m * 16 + (lane >> 4) * 4 + j;
        int col = wc * 64 + nn * 16 + (lane & 15);
        float v = acc[m][nn][j];
        if (BIAS) v += bias[o0 + row];
        Cb[(size_t)row * N + col] = v;
      }
}

// ---- q softmax over D=32 (axis=-2), scale folded in; in place ----
__global__ __launch_bounds__(256) void k_qsoftmax(float* __restrict__ qkv) {
  int idx = blockIdx.x * 256 + threadIdx.x;
  int n = idx & (N - 1);
  int bh = idx >> 12;
  int b = bh >> 2, h = bh & 3;
  float* base = qkv + ((size_t)b * O3 + h * D) * N + n;
  float v[D];
  float m = -1e30f;
  #pragma unroll
  for (int d = 0; d < D; ++d) { v[d] = base[(size_t)d * N]; m = fmaxf(m, v[d]); }
  float s = 0.f;
  #pragma unroll
  for (int d = 0; d < D; ++d) { v[d] = expf(v[d] - m); s += v[d]; }
  float rs = QSCALE / s;
  #pragma unroll
  for (int d = 0; d < D; ++d) base[(size_t)d * N] = v[d] * rs;
}

// ---- k softmax over N=4096 (axis=-1); one block per row; in place ----
__global__ __launch_bounds__(256) void k_ksoftmax(float* __restrict__ qkv) {
  __shared__ float red[4];
  int r = blockIdx.x;
  int b = r >> 7, rem = r & 127;
  float* row = qkv + ((size_t)b * O3 + HID + rem) * N;
  int t = threadIdx.x;
  float v[16];
  float m = -1e30f;
  #pragma unroll
  for (int i = 0; i < 16; ++i) { v[i] = row[i * 256 + t]; m = fmaxf(m, v[i]); }
  #pragma unroll
  for (int off = 32; off; off >>= 1) m = fmaxf(m, __shfl_xor(m, off));
  if ((t & 63) == 0) red[t >> 6] = m;
  __syncthreads();
  m = fmaxf(fmaxf(red[0], red[1]), fmaxf(red[2], red[3]));
  __syncthreads();
  float s = 0.f;
  #pragma unroll
  for (int i = 0; i < 16; ++i) { v[i] = expf(v[i] - m); s += v[i]; }
  #pragma unroll
  for (int off = 32; off; off >>= 1) s += __shfl_xor(s, off);
  if ((t & 63) == 0) red[t >> 6] = s;
  __syncthreads();
  s = red[0] + red[1] + red[2] + red[3];
  float rs = 1.f / s;
  #pragma unroll
  for (int i = 0; i < 16; ++i) row[i * 256 + t] = v[i] * rs;
}

// ---- context[b,h,d,e] = sum_n k[d,n]*v[e,n] ----
__global__ __launch_bounds__(256) void k_context(const float* __restrict__ qkv,
                                                 float* __restrict__ ctx) {
  __shared__ float kt[32 * 129];
  __shared__ float vt[32 * 129];
  int bh = blockIdx.x;
  int b = bh >> 2, h = bh & 3;
  int t = threadIdx.x;
  int d = t >> 3, e0 = (t & 7) * 4;
  float acc[4] = {0.f, 0.f, 0.f, 0.f};
  const float* kbase = qkv + ((size_t)b * O3 + HID + h * D) * N;
  const float* vbase = qkv + ((size_t)b * O3 + 2 * HID + h * D) * N;
  for (int n0 = 0; n0 < N; n0 += 128) {
    __syncthreads();
    #pragma unroll
    for (int j = 0; j < 16; ++j) {
      int f = j * 256 + t;
      int row = f >> 7, col = f & 127;
      kt[row * 129 + col] = kbase[(size_t)row * N + n0 + col];
      vt[row * 129 + col] = vbase[(size_t)row * N + n0 + col];
    }
    __syncthreads();
    for (int nn = 0; nn < 128; ++nn) {
      float kd = kt[d * 129 + nn];
      #pragma unroll
      for (int j = 0; j < 4; ++j) acc[j] += kd * vt[(e0 + j) * 129 + nn];
    }
  }
  float* cb = ctx + ((size_t)bh * D + d) * D + e0;
  #pragma unroll
  for (int j = 0; j < 4; ++j) cb[j] = acc[j];
}

// ---- out2bf[b][n][h*32+e] = bf16( sum_d ctx[b,h,d,e] * q[b,h,d,n] ) ----
__global__ __launch_bounds__(256) void k_out2(const float* __restrict__ qkv,
                                              const float* __restrict__ ctx,
                                              ushort* __restrict__ out2bf) {
  __shared__ float cl[D * D];
  int t = threadIdx.x;
  int n = blockIdx.x * 256 + t;
  int bh = blockIdx.y;
  int b = bh >> 2, h = bh & 3;
  #pragma unroll
  for (int j = 0; j < 4; ++j) cl[j * 256 + t] = ctx[(size_t)bh * D * D + j * 256 + t];
  __syncthreads();
  float q[D];
  const float* qb = qkv + ((size_t)b * O3 + h * D) * N + n;
  #pragma unroll
  for (int d = 0; d < D; ++d) q[d] = qb[(size_t)d * N];
  float a[D];
  #pragma unroll
  for (int e = 0; e < D; ++e) {
    float s = 0.f;
    #pragma unroll
    for (int d = 0; d < D; ++d) s += cl[d * D + e] * q[d];
    a[e] = s;
  }
  ushort* ob = out2bf + ((size_t)(b * N + n)) * HID + h * D;
  #pragma unroll
  for (int g = 0; g < 4; ++g) {
    union { ushort s[8]; uint4 v; } u;
    #pragma unroll
    for (int j = 0; j < 8; ++j) u.s[j] = f2bf(a[g * 8 + j]);
    *(uint4*)(ob + g * 8) = u.v;
  }
}

// ---- fused final rmsnorm (in place on out) ----
__global__ __launch_bounds__(256) void k_finalnorm(float* __restrict__ out,
                                                   const float* __restrict__ g) {
  __shared__ float red[4][64];
  __shared__ float invs[64];
  int t = threadIdx.x, w4 = t >> 6, ln = t & 63;
  int b = blockIdx.y, n0 = blockIdx.x * 64;
  float* ob = out + (size_t)b * C * N + n0;
  float ss = 0.f;
  #pragma unroll
  for (int it = 0; it < 64; ++it) {
    int c = it * 4 + w4;
    float v = ob[(size_t)c * N + ln];
    ss += v * v;
  }
  red[w4][ln] = ss;
  __syncthreads();
  if (t < 64) {
    float tot = red[0][t] + red[1][t] + red[2][t] + red[3][t];
    invs[t] = RMS_MUL / fmaxf(sqrtf(tot), EPS);
  }
  __syncthreads();
  float inv = invs[ln];
  #pragma unroll
  for (int it = 0; it < 64; ++it) {
    int c = it * 4 + w4;
    size_t idx = (size_t)c * N + ln;
    ob[idx] = ob[idx] * inv * g[c];
  }
}

extern "C" void kernel_launch(void* const* d_in, const int* in_sizes, int n_in,
                              void* d_out, int out_size, void* d_ws, size_t ws_size,
                              hipStream_t stream) {
  const float* x    = (const float*)d_in[0];
  const float* gn   = (const float*)d_in[1];
  const float* wqkv = (const float*)d_in[2];
  const float* wout = (const float*)d_in[3];
  const float* bout = (const float*)d_in[4];
  const float* gout = (const float*)d_in[5];
  float* out = (float*)d_out;
  float* ws  = (float*)d_ws;

  float*  qkv    = ws;                             // 25,165,824 f
  ushort* xbf    = (ushort*)(ws + 25165824);       // 16,777,216 bf16 (32MB)
  ushort* out2bf = xbf;                            // aliases xbf (dead after GEMM1)
  ushort* wA     = (ushort*)(ws + 33554432);       //    98,304 bf16
  ushort* wB     = (ushort*)(ws + 33603584);       //    32,768 bf16
  float*  ctx    = ws + 33619968;                  //    65,536 f
  // total: 33,685,504 floats = 134.7 MB

  k_prep_w  <<<512, 256, 0, stream>>>(wqkv, gn, wout, wA, wB);
  k_prep_x  <<<dim3(64, 16), 256, 0, stream>>>(x, xbf);
  k_gemm<256, false><<<dim3(32, 3, 16), 256, 0, stream>>>(wA, xbf, nullptr, qkv, O3);
  k_qsoftmax<<<1024, 256, 0, stream>>>(qkv);
  k_ksoftmax<<<2048, 256, 0, stream>>>(qkv);
  k_context <<<64, 256, 0, stream>>>(qkv, ctx);
  k_out2    <<<dim3(16, 64), 256, 0, stream>>>(qkv, ctx, out2bf);
  k_gemm<128, true><<<dim3(32, 2, 16), 256, 0, stream>>>(wB, out2bf, bout, out, C);
  k_finalnorm<<<dim3(64, 16), 256, 0, stream>>>(out, gout);
}

// Round 3
// 171.805 us; speedup vs baseline: 2.9952x; 1.5343x over previous
//
// R3: split k_context over N (2048 blocks) + deterministic partial reduce.
//     Rest identical to R2.
#include <hip/hip_runtime.h>
#include <hip/hip_bf16.h>
#include <math.h>

#define B 16
#define C 256
#define H 4
#define D 32
#define HID 128
#define O3 384
#define N 4096
#define NSPLIT 32
#define QSCALE 0.17677669529663687f  // 1/sqrt(32)
#define RMS_MUL 16.0f                // sqrt(256)
#define EPS 1e-12f

typedef __attribute__((ext_vector_type(8))) short short8;
typedef __attribute__((ext_vector_type(4))) float f32x4;

__device__ __forceinline__ ushort f2bf(float f) {
  __hip_bfloat16 h = __float2bfloat16(f);
  return *(ushort*)&h;
}
__device__ __forceinline__ float bf2f(ushort u) {
  unsigned int v = ((unsigned int)u) << 16;
  return *(float*)&v;
}
__device__ __forceinline__ void load_lds16(const void* g, void* l) {
  __builtin_amdgcn_global_load_lds((const __attribute__((address_space(1))) void*)g,
                                   (__attribute__((address_space(3))) void*)l, 16, 0, 0);
}

// ---- weight prep: wA[o][c] = bf16(wqkv[o][c]*g[c]); wB = bf16(wout) ----
__global__ __launch_bounds__(256) void k_prep_w(const float* __restrict__ wqkv,
                                                const float* __restrict__ g,
                                                const float* __restrict__ wout,
                                                ushort* __restrict__ wA,
                                                ushort* __restrict__ wB) {
  int idx = blockIdx.x * 256 + threadIdx.x;
  if (idx < O3 * C) {
    wA[idx] = f2bf(wqkv[idx] * g[idx & (C - 1)]);
  } else {
    int j = idx - O3 * C;
    wB[j] = f2bf(wout[j]);
  }
}

// ---- x prep: rmsnorm + transpose to xbf[b][n][c] (bf16, c contiguous) ----
__global__ __launch_bounds__(256) void k_prep_x(const float* __restrict__ x,
                                                ushort* __restrict__ xbf) {
  __shared__ ushort xl[C][64];
  __shared__ float red[4][64];
  __shared__ float invs[64];
  int t = threadIdx.x, w4 = t >> 6, ln = t & 63;
  int b = blockIdx.y, n0 = blockIdx.x * 64;
  const float* xb = x + (size_t)b * C * N + n0;
  float ss = 0.f;
  #pragma unroll
  for (int it = 0; it < 64; ++it) {
    int c = it * 4 + w4;
    float v = xb[(size_t)c * N + ln];
    ss += v * v;
    xl[c][ln] = f2bf(v);
  }
  red[w4][ln] = ss;
  __syncthreads();
  if (t < 64) {
    float tot = red[0][t] + red[1][t] + red[2][t] + red[3][t];
    invs[t] = RMS_MUL / fmaxf(sqrtf(tot), EPS);
  }
  __syncthreads();
  float inv = invs[ln];
  ushort* dst = xbf + ((size_t)(b * N + n0 + ln)) * C + w4 * 64;
  #pragma unroll
  for (int ch = 0; ch < 8; ++ch) {
    union { ushort s[8]; uint4 v; } u;
    #pragma unroll
    for (int j = 0; j < 8; ++j)
      u.s[j] = f2bf(bf2f(xl[w4 * 64 + ch * 8 + j][ln]) * inv);
    *(uint4*)(dst + ch * 8) = u.v;
  }
}

// ---- MFMA GEMM (C = A * B^T): A[M][K] bf16, Bm[b][4096][K] bf16, Cout[b][M][4096] f32 ----
template <int K, bool BIAS>
__global__ __launch_bounds__(256) void k_gemm(const ushort* __restrict__ A,
                                              const ushort* __restrict__ Bm,
                                              const float* __restrict__ bias,
                                              float* __restrict__ Cout, int M) {
  __shared__ ushort Abuf[128 * 64];
  __shared__ ushort Bbuf[128 * 64];
  int t = threadIdx.x;
  int lane = t & 63, w = t >> 6;
  int wr = w >> 1, wc = w & 1;
  int n0 = blockIdx.x * 128, o0 = blockIdx.y * 128, b = blockIdx.z;
  const ushort* Ab = A + (size_t)o0 * K;
  const ushort* Bb = Bm + ((size_t)b * N + n0) * K;
  f32x4 acc[4][4] = {};
  for (int k0 = 0; k0 < K; k0 += 64) {
    #pragma unroll
    for (int i = 0; i < 4; ++i) {
      int chunk = w * 4 + i;
      int row = chunk * 8 + (lane >> 3);
      int col = k0 + (lane & 7) * 8;
      load_lds16(Ab + (size_t)row * K + col, Abuf + chunk * 512);
      load_lds16(Bb + (size_t)row * K + col, Bbuf + chunk * 512);
    }
    __syncthreads();
    #pragma unroll
    for (int kk = 0; kk < 2; ++kk) {
      short8 af[4], bfr[4];
      #pragma unroll
      for (int m = 0; m < 4; ++m)
        af[m] = *(const short8*)&Abuf[(wr * 64 + m * 16 + (lane & 15)) * 64 + kk * 32 + (lane >> 4) * 8];
      #pragma unroll
      for (int nn = 0; nn < 4; ++nn)
        bfr[nn] = *(const short8*)&Bbuf[(wc * 64 + nn * 16 + (lane & 15)) * 64 + kk * 32 + (lane >> 4) * 8];
      #pragma unroll
      for (int m = 0; m < 4; ++m)
        #pragma unroll
        for (int nn = 0; nn < 4; ++nn)
          acc[m][nn] = __builtin_amdgcn_mfma_f32_16x16x32_bf16(af[m], bfr[nn], acc[m][nn], 0, 0, 0);
    }
    __syncthreads();
  }
  float* Cb = Cout + ((size_t)b * M + o0) * N + n0;
  #pragma unroll
  for (int m = 0; m < 4; ++m)
    #pragma unroll
    for (int nn = 0; nn < 4; ++nn)
      #pragma unroll
      for (int j = 0; j < 4; ++j) {
        int row = wr * 64 + m * 16 + (lane >> 4) * 4 + j;
        int col = wc * 64 + nn * 16 + (lane & 15);
        float v = acc[m][nn][j];
        if (BIAS) v += bias[o0 + row];
        Cb[(size_t)row * N + col] = v;
      }
}

// ---- q softmax over D=32 (axis=-2), scale folded in; in place ----
__global__ __launch_bounds__(256) void k_qsoftmax(float* __restrict__ qkv) {
  int idx = blockIdx.x * 256 + threadIdx.x;
  int n = idx & (N - 1);
  int bh = idx >> 12;
  int b = bh >> 2, h = bh & 3;
  float* base = qkv + ((size_t)b * O3 + h * D) * N + n;
  float v[D];
  float m = -1e30f;
  #pragma unroll
  for (int d = 0; d < D; ++d) { v[d] = base[(size_t)d * N]; m = fmaxf(m, v[d]); }
  float s = 0.f;
  #pragma unroll
  for (int d = 0; d < D; ++d) { v[d] = expf(v[d] - m); s += v[d]; }
  float rs = QSCALE / s;
  #pragma unroll
  for (int d = 0; d < D; ++d) base[(size_t)d * N] = v[d] * rs;
}

// ---- k softmax over N=4096 (axis=-1); one block per row; in place ----
__global__ __launch_bounds__(256) void k_ksoftmax(float* __restrict__ qkv) {
  __shared__ float red[4];
  int r = blockIdx.x;
  int b = r >> 7, rem = r & 127;
  float* row = qkv + ((size_t)b * O3 + HID + rem) * N;
  int t = threadIdx.x;
  float v[16];
  float m = -1e30f;
  #pragma unroll
  for (int i = 0; i < 16; ++i) { v[i] = row[i * 256 + t]; m = fmaxf(m, v[i]); }
  #pragma unroll
  for (int off = 32; off; off >>= 1) m = fmaxf(m, __shfl_xor(m, off));
  if ((t & 63) == 0) red[t >> 6] = m;
  __syncthreads();
  m = fmaxf(fmaxf(red[0], red[1]), fmaxf(red[2], red[3]));
  __syncthreads();
  float s = 0.f;
  #pragma unroll
  for (int i = 0; i < 16; ++i) { v[i] = expf(v[i] - m); s += v[i]; }
  #pragma unroll
  for (int off = 32; off; off >>= 1) s += __shfl_xor(s, off);
  if ((t & 63) == 0) red[t >> 6] = s;
  __syncthreads();
  s = red[0] + red[1] + red[2] + red[3];
  float rs = 1.f / s;
  #pragma unroll
  for (int i = 0; i < 16; ++i) row[i * 256 + t] = v[i] * rs;
}

// ---- split context: ctxp[s][bh][d][e] = sum over 128-wide slab of k[d,n]*v[e,n] ----
__global__ __launch_bounds__(256) void k_context(const float* __restrict__ qkv,
                                                 float* __restrict__ ctxp) {
  __shared__ float kt[32 * 129];
  __shared__ float vt[32 * 129];
  int s = blockIdx.x;                 // 0..31 split
  int bh = blockIdx.y;                // 0..63
  int b = bh >> 2, h = bh & 3;
  int t = threadIdx.x;
  int d = t >> 3, e0 = (t & 7) * 4;
  int n0 = s * 128;
  const float* kbase = qkv + ((size_t)b * O3 + HID + h * D) * N;
  const float* vbase = qkv + ((size_t)b * O3 + 2 * HID + h * D) * N;
  #pragma unroll
  for (int j = 0; j < 16; ++j) {
    int f = j * 256 + t;
    int row = f >> 7, col = f & 127;
    kt[row * 129 + col] = kbase[(size_t)row * N + n0 + col];
    vt[row * 129 + col] = vbase[(size_t)row * N + n0 + col];
  }
  __syncthreads();
  float acc[4] = {0.f, 0.f, 0.f, 0.f};
  for (int nn = 0; nn < 128; ++nn) {
    float kd = kt[d * 129 + nn];
    #pragma unroll
    for (int j = 0; j < 4; ++j) acc[j] += kd * vt[(e0 + j) * 129 + nn];
  }
  f32x4 v = {acc[0], acc[1], acc[2], acc[3]};
  *(f32x4*)(ctxp + ((size_t)(s * 64 + bh) * 1024) + d * 32 + e0) = v;
}

// ---- reduce partials: ctx[i] = sum_s ctxp[s][i] ----
__global__ __launch_bounds__(256) void k_redctx(const float* __restrict__ ctxp,
                                                float* __restrict__ ctx) {
  int idx = blockIdx.x * 256 + threadIdx.x;      // 0..65535
  float s = 0.f;
  #pragma unroll
  for (int i = 0; i < NSPLIT; ++i) s += ctxp[(size_t)i * 65536 + idx];
  ctx[idx] = s;
}

// ---- out2bf[b][n][h*32+e] = bf16( sum_d ctx[b,h,d,e] * q[b,h,d,n] ) ----
__global__ __launch_bounds__(256) void k_out2(const float* __restrict__ qkv,
                                              const float* __restrict__ ctx,
                                              ushort* __restrict__ out2bf) {
  __shared__ float cl[D * D];
  int t = threadIdx.x;
  int n = blockIdx.x * 256 + t;
  int bh = blockIdx.y;
  int b = bh >> 2, h = bh & 3;
  #pragma unroll
  for (int j = 0; j < 4; ++j) cl[j * 256 + t] = ctx[(size_t)bh * D * D + j * 256 + t];
  __syncthreads();
  float q[D];
  const float* qb = qkv + ((size_t)b * O3 + h * D) * N + n;
  #pragma unroll
  for (int d = 0; d < D; ++d) q[d] = qb[(size_t)d * N];
  float a[D];
  #pragma unroll
  for (int e = 0; e < D; ++e) {
    float s = 0.f;
    #pragma unroll
    for (int d = 0; d < D; ++d) s += cl[d * D + e] * q[d];
    a[e] = s;
  }
  ushort* ob = out2bf + ((size_t)(b * N + n)) * HID + h * D;
  #pragma unroll
  for (int g = 0; g < 4; ++g) {
    union { ushort s[8]; uint4 v; } u;
    #pragma unroll
    for (int j = 0; j < 8; ++j) u.s[j] = f2bf(a[g * 8 + j]);
    *(uint4*)(ob + g * 8) = u.v;
  }
}

// ---- fused final rmsnorm (in place on out) ----
__global__ __launch_bounds__(256) void k_finalnorm(float* __restrict__ out,
                                                   const float* __restrict__ g) {
  __shared__ float red[4][64];
  __shared__ float invs[64];
  int t = threadIdx.x, w4 = t >> 6, ln = t & 63;
  int b = blockIdx.y, n0 = blockIdx.x * 64;
  float* ob = out + (size_t)b * C * N + n0;
  float ss = 0.f;
  #pragma unroll
  for (int it = 0; it < 64; ++it) {
    int c = it * 4 + w4;
    float v = ob[(size_t)c * N + ln];
    ss += v * v;
  }
  red[w4][ln] = ss;
  __syncthreads();
  if (t < 64) {
    float tot = red[0][t] + red[1][t] + red[2][t] + red[3][t];
    invs[t] = RMS_MUL / fmaxf(sqrtf(tot), EPS);
  }
  __syncthreads();
  float inv = invs[ln];
  #pragma unroll
  for (int it = 0; it < 64; ++it) {
    int c = it * 4 + w4;
    size_t idx = (size_t)c * N + ln;
    ob[idx] = ob[idx] * inv * g[c];
  }
}

extern "C" void kernel_launch(void* const* d_in, const int* in_sizes, int n_in,
                              void* d_out, int out_size, void* d_ws, size_t ws_size,
                              hipStream_t stream) {
  const float* x    = (const float*)d_in[0];
  const float* gn   = (const float*)d_in[1];
  const float* wqkv = (const float*)d_in[2];
  const float* wout = (const float*)d_in[3];
  const float* bout = (const float*)d_in[4];
  const float* gout = (const float*)d_in[5];
  float* out = (float*)d_out;
  float* ws  = (float*)d_ws;

  float*  qkv    = ws;                             // 25,165,824 f
  ushort* xbf    = (ushort*)(ws + 25165824);       // 16,777,216 bf16 (32MB)
  ushort* out2bf = xbf;                            // aliases xbf (dead after GEMM1)
  float*  ctxp   = (float*)xbf;                    // 2,097,152 f — alive only context->redctx
  ushort* wA     = (ushort*)(ws + 33554432);
  ushort* wB     = (ushort*)(ws + 33603584);
  float*  ctx    = ws + 33619968;
  // total: 33,685,504 floats = 134.7 MB

  k_prep_w  <<<512, 256, 0, stream>>>(wqkv, gn, wout, wA, wB);
  k_prep_x  <<<dim3(64, 16), 256, 0, stream>>>(x, xbf);
  k_gemm<256, false><<<dim3(32, 3, 16), 256, 0, stream>>>(wA, xbf, nullptr, qkv, O3);
  k_qsoftmax<<<1024, 256, 0, stream>>>(qkv);
  k_ksoftmax<<<2048, 256, 0, stream>>>(qkv);
  k_context <<<dim3(NSPLIT, 64), 256, 0, stream>>>(qkv, ctxp);   // ctxp aliases xbf (xbf dead)
  k_redctx  <<<256, 256, 0, stream>>>(ctxp, ctx);
  k_out2    <<<dim3(16, 64), 256, 0, stream>>>(qkv, ctx, out2bf);
  k_gemm<128, true><<<dim3(32, 2, 16), 256, 0, stream>>>(wB, out2bf, bout, out, C);
  k_finalnorm<<<dim3(64, 16), 256, 0, stream>>>(out, gout);
}

// Round 4
// 128.862 us; speedup vs baseline: 3.9934x; 1.3332x over previous
//
// R4: fuse q-softmax into GEMM1 epilogue (in-register shfl), k-softmax -> row
//     stats folded into context staging, final rmsnorm fused into GEMM2
//     (BM=256 x BN=64 tile). Removes k_qsoftmax/k_ksoftmax/k_finalnorm.
#include <hip/hip_runtime.h>
#include <hip/hip_bf16.h>
#include <math.h>

#define B 16
#define C 256
#define H 4
#define D 32
#define HID 128
#define O3 384
#define N 4096
#define NSPLIT 32
#define QSCALE 0.17677669529663687f  // 1/sqrt(32)
#define RMS_MUL 16.0f                // sqrt(256)
#define EPS 1e-12f

typedef __attribute__((ext_vector_type(8))) short short8;
typedef __attribute__((ext_vector_type(4))) float f32x4;

__device__ __forceinline__ ushort f2bf(float f) {
  __hip_bfloat16 h = __float2bfloat16(f);
  return *(ushort*)&h;
}
__device__ __forceinline__ float bf2f(ushort u) {
  unsigned int v = ((unsigned int)u) << 16;
  return *(float*)&v;
}
__device__ __forceinline__ void load_lds16(const void* g, void* l) {
  __builtin_amdgcn_global_load_lds((const __attribute__((address_space(1))) void*)g,
                                   (__attribute__((address_space(3))) void*)l, 16, 0, 0);
}

// ---- weight prep: wA[o][c] = bf16(wqkv[o][c]*g[c]); wB = bf16(wout) ----
__global__ __launch_bounds__(256) void k_prep_w(const float* __restrict__ wqkv,
                                                const float* __restrict__ g,
                                                const float* __restrict__ wout,
                                                ushort* __restrict__ wA,
                                                ushort* __restrict__ wB) {
  int idx = blockIdx.x * 256 + threadIdx.x;
  if (idx < O3 * C) {
    wA[idx] = f2bf(wqkv[idx] * g[idx & (C - 1)]);
  } else {
    int j = idx - O3 * C;
    wB[j] = f2bf(wout[j]);
  }
}

// ---- x prep: rmsnorm + transpose to xbf[b][n][c] (bf16, c contiguous) ----
__global__ __launch_bounds__(256) void k_prep_x(const float* __restrict__ x,
                                                ushort* __restrict__ xbf) {
  __shared__ ushort xl[C][64];
  __shared__ float red[4][64];
  __shared__ float invs[64];
  int t = threadIdx.x, w4 = t >> 6, ln = t & 63;
  int b = blockIdx.y, n0 = blockIdx.x * 64;
  const float* xb = x + (size_t)b * C * N + n0;
  float ss = 0.f;
  #pragma unroll
  for (int it = 0; it < 64; ++it) {
    int c = it * 4 + w4;
    float v = xb[(size_t)c * N + ln];
    ss += v * v;
    xl[c][ln] = f2bf(v);
  }
  red[w4][ln] = ss;
  __syncthreads();
  if (t < 64) {
    float tot = red[0][t] + red[1][t] + red[2][t] + red[3][t];
    invs[t] = RMS_MUL / fmaxf(sqrtf(tot), EPS);
  }
  __syncthreads();
  float inv = invs[ln];
  ushort* dst = xbf + ((size_t)(b * N + n0 + ln)) * C + w4 * 64;
  #pragma unroll
  for (int ch = 0; ch < 8; ++ch) {
    union { ushort s[8]; uint4 v; } u;
    #pragma unroll
    for (int j = 0; j < 8; ++j)
      u.s[j] = f2bf(bf2f(xl[w4 * 64 + ch * 8 + j][ln]) * inv);
    *(uint4*)(dst + ch * 8) = u.v;
  }
}

// ---- GEMM1: qkv[b][o][n] = wA[o][:] . xbf[b][n][:]; q-softmax fused (y==0) ----
__global__ __launch_bounds__(256) void k_gemm1(const ushort* __restrict__ A,
                                               const ushort* __restrict__ Bm,
                                               float* __restrict__ Cout) {
  const int K = 256;
  __shared__ ushort Abuf[128 * 64];
  __shared__ ushort Bbuf[128 * 64];
  int t = threadIdx.x;
  int lane = t & 63, w = t >> 6;
  int wr = w >> 1, wc = w & 1;
  int n0 = blockIdx.x * 128, o0 = blockIdx.y * 128, b = blockIdx.z;
  const ushort* Ab = A + (size_t)o0 * K;
  const ushort* Bb = Bm + ((size_t)b * N + n0) * K;
  f32x4 acc[4][4] = {};
  for (int k0 = 0; k0 < K; k0 += 64) {
    #pragma unroll
    for (int i = 0; i < 4; ++i) {
      int chunk = w * 4 + i;
      int row = chunk * 8 + (lane >> 3);
      int col = k0 + (lane & 7) * 8;
      load_lds16(Ab + (size_t)row * K + col, Abuf + chunk * 512);
      load_lds16(Bb + (size_t)row * K + col, Bbuf + chunk * 512);
    }
    __syncthreads();
    #pragma unroll
    for (int kk = 0; kk < 2; ++kk) {
      short8 af[4], bfr[4];
      #pragma unroll
      for (int m = 0; m < 4; ++m)
        af[m] = *(const short8*)&Abuf[(wr * 64 + m * 16 + (lane & 15)) * 64 + kk * 32 + (lane >> 4) * 8];
      #pragma unroll
      for (int nn = 0; nn < 4; ++nn)
        bfr[nn] = *(const short8*)&Bbuf[(wc * 64 + nn * 16 + (lane & 15)) * 64 + kk * 32 + (lane >> 4) * 8];
      #pragma unroll
      for (int m = 0; m < 4; ++m)
        #pragma unroll
        for (int nn = 0; nn < 4; ++nn)
          acc[m][nn] = __builtin_amdgcn_mfma_f32_16x16x32_bf16(af[m], bfr[nn], acc[m][nn], 0, 0, 0);
    }
    __syncthreads();
  }
  if (blockIdx.y == 0) {
    // q-softmax over d=32 (rows wr*64 + hh*32 + [0,32)) per column, in-register.
    #pragma unroll
    for (int hh = 0; hh < 2; ++hh) {
      #pragma unroll
      for (int nn = 0; nn < 4; ++nn) {
        int m0 = hh * 2;
        float pm = -1e30f;
        #pragma unroll
        for (int mi = 0; mi < 2; ++mi)
          #pragma unroll
          for (int j = 0; j < 4; ++j) pm = fmaxf(pm, acc[m0 + mi][nn][j]);
        pm = fmaxf(pm, __shfl_xor(pm, 16));
        pm = fmaxf(pm, __shfl_xor(pm, 32));
        float e[2][4], ps = 0.f;
        #pragma unroll
        for (int mi = 0; mi < 2; ++mi)
          #pragma unroll
          for (int j = 0; j < 4; ++j) {
            e[mi][j] = __expf(acc[m0 + mi][nn][j] - pm);
            ps += e[mi][j];
          }
        ps += __shfl_xor(ps, 16);
        ps += __shfl_xor(ps, 32);
        float rs = QSCALE / ps;
        #pragma unroll
        for (int mi = 0; mi < 2; ++mi)
          #pragma unroll
          for (int j = 0; j < 4; ++j) acc[m0 + mi][nn][j] = e[mi][j] * rs;
      }
    }
  }
  float* Cb = Cout + ((size_t)b * O3 + o0) * N + n0;
  #pragma unroll
  for (int m = 0; m < 4; ++m)
    #pragma unroll
    for (int nn = 0; nn < 4; ++nn)
      #pragma unroll
      for (int j = 0; j < 4; ++j) {
        int row = wr * 64 + m * 16 + (lane >> 4) * 4 + j;
        int col = wc * 64 + nn * 16 + (lane & 15);
        Cb[(size_t)row * N + col] = acc[m][nn][j];
      }
}

// ---- k row stats: kstat[r] = (max_n k, 1/sum_n exp(k-max)) ----
__global__ __launch_bounds__(256) void k_krowstat(const float* __restrict__ qkv,
                                                  float2* __restrict__ kstat) {
  __shared__ float red[4];
  int r = blockIdx.x;                 // 0..2047
  int b = r >> 7, rem = r & 127;
  const float* row = qkv + ((size_t)b * O3 + HID + rem) * N;
  int t = threadIdx.x;
  float v[16];
  float m = -1e30f;
  #pragma unroll
  for (int i = 0; i < 16; ++i) { v[i] = row[i * 256 + t]; m = fmaxf(m, v[i]); }
  #pragma unroll
  for (int off = 32; off; off >>= 1) m = fmaxf(m, __shfl_xor(m, off));
  if ((t & 63) == 0) red[t >> 6] = m;
  __syncthreads();
  m = fmaxf(fmaxf(red[0], red[1]), fmaxf(red[2], red[3]));
  __syncthreads();
  float s = 0.f;
  #pragma unroll
  for (int i = 0; i < 16; ++i) s += __expf(v[i] - m);
  #pragma unroll
  for (int off = 32; off; off >>= 1) s += __shfl_xor(s, off);
  if ((t & 63) == 0) red[t >> 6] = s;
  __syncthreads();
  if (t == 0) {
    float tot = red[0] + red[1] + red[2] + red[3];
    kstat[r] = make_float2(m, 1.f / tot);
  }
}

// ---- split context with k-softmax folded into staging ----
__global__ __launch_bounds__(256) void k_context(const float* __restrict__ qkv,
                                                 const float2* __restrict__ kstat,
                                                 float* __restrict__ ctxp) {
  __shared__ float kt[32 * 129];
  __shared__ float vt[32 * 129];
  __shared__ float km[32], krs[32];
  int s = blockIdx.x;
  int bh = blockIdx.y;
  int b = bh >> 2, h = bh & 3;
  int t = threadIdx.x;
  if (t < 32) {
    float2 st = kstat[bh * D + t];
    km[t] = st.x; krs[t] = st.y;
  }
  __syncthreads();
  int d = t >> 3, e0 = (t & 7) * 4;
  int n0 = s * 128;
  const float* kbase = qkv + ((size_t)b * O3 + HID + h * D) * N;
  const float* vbase = qkv + ((size_t)b * O3 + 2 * HID + h * D) * N;
  #pragma unroll
  for (int j = 0; j < 16; ++j) {
    int f = j * 256 + t;
    int row = f >> 7, col = f & 127;
    kt[row * 129 + col] = __expf(kbase[(size_t)row * N + n0 + col] - km[row]) * krs[row];
    vt[row * 129 + col] = vbase[(size_t)row * N + n0 + col];
  }
  __syncthreads();
  float acc[4] = {0.f, 0.f, 0.f, 0.f};
  for (int nn = 0; nn < 128; ++nn) {
    float kd = kt[d * 129 + nn];
    #pragma unroll
    for (int j = 0; j < 4; ++j) acc[j] += kd * vt[(e0 + j) * 129 + nn];
  }
  f32x4 v = {acc[0], acc[1], acc[2], acc[3]};
  *(f32x4*)(ctxp + ((size_t)(s * 64 + bh) * 1024) + d * 32 + e0) = v;
}

// ---- reduce partials: ctx[i] = sum_s ctxp[s][i] ----
__global__ __launch_bounds__(256) void k_redctx(const float* __restrict__ ctxp,
                                                float* __restrict__ ctx) {
  int idx = blockIdx.x * 256 + threadIdx.x;
  float s = 0.f;
  #pragma unroll
  for (int i = 0; i < NSPLIT; ++i) s += ctxp[(size_t)i * 65536 + idx];
  ctx[idx] = s;
}

// ---- out2bf[b][n][h*32+e] = bf16( sum_d ctx[b,h,d,e] * q[b,h,d,n] ) ----
__global__ __launch_bounds__(256) void k_out2(const float* __restrict__ qkv,
                                              const float* __restrict__ ctx,
                                              ushort* __restrict__ out2bf) {
  __shared__ float cl[D * D];
  int t = threadIdx.x;
  int n = blockIdx.x * 256 + t;
  int bh = blockIdx.y;
  int b = bh >> 2, h = bh & 3;
  #pragma unroll
  for (int j = 0; j < 4; ++j) cl[j * 256 + t] = ctx[(size_t)bh * D * D + j * 256 + t];
  __syncthreads();
  float q[D];
  const float* qb = qkv + ((size_t)b * O3 + h * D) * N + n;
  #pragma unroll
  for (int d = 0; d < D; ++d) q[d] = qb[(size_t)d * N];
  float a[D];
  #pragma unroll
  for (int e = 0; e < D; ++e) {
    float s = 0.f;
    #pragma unroll
    for (int d = 0; d < D; ++d) s += cl[d * D + e] * q[d];
    a[e] = s;
  }
  ushort* ob = out2bf + ((size_t)(b * N + n)) * HID + h * D;
  #pragma unroll
  for (int g = 0; g < 4; ++g) {
    union { ushort s[8]; uint4 v; } u;
    #pragma unroll
    for (int j = 0; j < 8; ++j) u.s[j] = f2bf(a[g * 8 + j]);
    *(uint4*)(ob + g * 8) = u.v;
  }
}

// ---- GEMM2 (BM=256 full-M x BN=64) + bias + fused final rmsnorm ----
__global__ __launch_bounds__(256) void k_gemm2(const ushort* __restrict__ A,
                                               const ushort* __restrict__ Bm,
                                               const float* __restrict__ bias,
                                               const float* __restrict__ g,
                                               float* __restrict__ outp) {
  const int K = HID;                  // 128
  __shared__ ushort Abuf[256 * 64];   // 32 KB
  __shared__ ushort Bbuf[64 * 64];    // 8 KB
  __shared__ float ssred[4][64];
  __shared__ float biasl[C], gl[C];
  int t = threadIdx.x;
  int lane = t & 63, w = t >> 6;
  int n0 = blockIdx.x * 64, b = blockIdx.z;
  biasl[t] = bias[t];
  gl[t] = g[t];
  const ushort* Bb = Bm + ((size_t)b * N + n0) * K;
  f32x4 acc[4][4] = {};
  for (int k0 = 0; k0 < K; k0 += 64) {
    #pragma unroll
    for (int i = 0; i < 8; ++i) {
      int chunk = w * 8 + i;                   // 0..31, rows 0..255
      int row = chunk * 8 + (lane >> 3);
      int col = k0 + (lane & 7) * 8;
      load_lds16(A + (size_t)row * K + col, Abuf + chunk * 512);
    }
    #pragma unroll
    for (int i = 0; i < 2; ++i) {
      int chunk = w * 2 + i;                   // 0..7, rows 0..63
      int row = chunk * 8 + (lane >> 3);
      int col = k0 + (lane & 7) * 8;
      load_lds16(Bb + (size_t)row * K + col, Bbuf + chunk * 512);
    }
    __syncthreads();
    #pragma unroll
    for (int kk = 0; kk < 2; ++kk) {
      short8 af[4], bfr[4];
      #pragma unroll
      for (int m = 0; m < 4; ++m)
        af[m] = *(const short8*)&Abuf[(w * 64 + m * 16 + (lane & 15)) * 64 + kk * 32 + (lane >> 4) * 8];
      #pragma unroll
      for (int nn = 0; nn < 4; ++nn)
        bfr[nn] = *(const short8*)&Bbuf[(nn * 16 + (lane & 15)) * 64 + kk * 32 + (lane >> 4) * 8];
      #pragma unroll
      for (int m = 0; m < 4; ++m)
        #pragma unroll
        for (int nn = 0; nn < 4; ++nn)
          acc[m][nn] = __builtin_amdgcn_mfma_f32_16x16x32_bf16(af[m], bfr[nn], acc[m][nn], 0, 0, 0);
    }
    __syncthreads();
  }
  // bias
  #pragma unroll
  for (int m = 0; m < 4; ++m)
    #pragma unroll
    for (int j = 0; j < 4; ++j) {
      int row = w * 64 + m * 16 + (lane >> 4) * 4 + j;
      float bv = biasl[row];
      #pragma unroll
      for (int nn = 0; nn < 4; ++nn) acc[m][nn][j] += bv;
    }
  // per-column sum of squares (this wave's 64 rows), then cross-wave via LDS
  float ssp[4];
  #pragma unroll
  for (int nn = 0; nn < 4; ++nn) {
    float s = 0.f;
    #pragma unroll
    for (int m = 0; m < 4; ++m)
      #pragma unroll
      for (int j = 0; j < 4; ++j) s += acc[m][nn][j] * acc[m][nn][j];
    s += __shfl_xor(s, 16);
    s += __shfl_xor(s, 32);
    ssp[nn] = s;
  }
  if ((lane >> 4) == 0) {
    #pragma unroll
    for (int nn = 0; nn < 4; ++nn) ssred[w][nn * 16 + (lane & 15)] = ssp[nn];
  }
  __syncthreads();
  float inv[4];
  #pragma unroll
  for (int nn = 0; nn < 4; ++nn) {
    int col = nn * 16 + (lane & 15);
    float tot = ssred[0][col] + ssred[1][col] + ssred[2][col] + ssred[3][col];
    inv[nn] = RMS_MUL / fmaxf(sqrtf(tot), EPS);
  }
  float* Cb = outp + (size_t)b * C * N + n0;
  #pragma unroll
  for (int m = 0; m < 4; ++m)
    #pragma unroll
    for (int j = 0; j < 4; ++j) {
      int row = w * 64 + m * 16 + (lane >> 4) * 4 + j;
      float gm = gl[row];
      #pragma unroll
      for (int nn = 0; nn < 4; ++nn) {
        int col = nn * 16 + (lane & 15);
        Cb[(size_t)row * N + col] = acc[m][nn][j] * inv[nn] * gm;
      }
    }
}

extern "C" void kernel_launch(void* const* d_in, const int* in_sizes, int n_in,
                              void* d_out, int out_size, void* d_ws, size_t ws_size,
                              hipStream_t stream) {
  const float* x    = (const float*)d_in[0];
  const float* gn   = (const float*)d_in[1];
  const float* wqkv = (const float*)d_in[2];
  const float* wout = (const float*)d_in[3];
  const float* bout = (const float*)d_in[4];
  const float* gout = (const float*)d_in[5];
  float* out = (float*)d_out;
  float* ws  = (float*)d_ws;

  float*  qkv    = ws;                             // 25,165,824 f
  ushort* xbf    = (ushort*)(ws + 25165824);       // 16,777,216 bf16 (32MB)
  ushort* out2bf = xbf;                            // aliases xbf (dead after GEMM1)
  float*  ctxp   = (float*)xbf;                    // 2M f — live context->redctx only
  float2* kstat  = (float2*)(ws + 29360128);       // 2048 float2 — live krowstat->context
  ushort* wA     = (ushort*)(ws + 33554432);
  ushort* wB     = (ushort*)(ws + 33603584);
  float*  ctx    = ws + 33619968;

  k_prep_w  <<<512, 256, 0, stream>>>(wqkv, gn, wout, wA, wB);
  k_prep_x  <<<dim3(64, 16), 256, 0, stream>>>(x, xbf);
  k_gemm1   <<<dim3(32, 3, 16), 256, 0, stream>>>(wA, xbf, qkv);
  k_krowstat<<<2048, 256, 0, stream>>>(qkv, kstat);
  k_context <<<dim3(NSPLIT, 64), 256, 0, stream>>>(qkv, kstat, ctxp);
  k_redctx  <<<256, 256, 0, stream>>>(ctxp, ctx);
  k_out2    <<<dim3(16, 64), 256, 0, stream>>>(qkv, ctx, out2bf);
  k_gemm2   <<<dim3(64, 1, 16), 256, 0, stream>>>(wB, out2bf, bout, gout, out);
}

// Round 5
// 119.029 us; speedup vs baseline: 4.3233x; 1.0826x over previous
//
// R5: q/k/v intermediates in bf16 (separate buffers, consumer layouts).
//     Saves ~80 MB of HBM traffic vs fp32 qkv. Rest same as R4.
#include <hip/hip_runtime.h>
#include <hip/hip_bf16.h>
#include <math.h>

#define B 16
#define C 256
#define H 4
#define D 32
#define HID 128
#define O3 384
#define N 4096
#define NSPLIT 32
#define QSCALE 0.17677669529663687f  // 1/sqrt(32)
#define RMS_MUL 16.0f                // sqrt(256)
#define EPS 1e-12f

typedef __attribute__((ext_vector_type(8))) short short8;
typedef __attribute__((ext_vector_type(4))) float f32x4;

__device__ __forceinline__ ushort f2bf(float f) {
  __hip_bfloat16 h = __float2bfloat16(f);
  return *(ushort*)&h;
}
__device__ __forceinline__ float bf2f(ushort u) {
  unsigned int v = ((unsigned int)u) << 16;
  return *(float*)&v;
}
__device__ __forceinline__ void load_lds16(const void* g, void* l) {
  __builtin_amdgcn_global_load_lds((const __attribute__((address_space(1))) void*)g,
                                   (__attribute__((address_space(3))) void*)l, 16, 0, 0);
}

// ---- weight prep: wA[o][c] = bf16(wqkv[o][c]*g[c]); wB = bf16(wout) ----
__global__ __launch_bounds__(256) void k_prep_w(const float* __restrict__ wqkv,
                                                const float* __restrict__ g,
                                                const float* __restrict__ wout,
                                                ushort* __restrict__ wA,
                                                ushort* __restrict__ wB) {
  int idx = blockIdx.x * 256 + threadIdx.x;
  if (idx < O3 * C) {
    wA[idx] = f2bf(wqkv[idx] * g[idx & (C - 1)]);
  } else {
    int j = idx - O3 * C;
    wB[j] = f2bf(wout[j]);
  }
}

// ---- x prep: rmsnorm + transpose to xbf[b][n][c] (bf16, c contiguous) ----
__global__ __launch_bounds__(256) void k_prep_x(const float* __restrict__ x,
                                                ushort* __restrict__ xbf) {
  __shared__ ushort xl[C][64];
  __shared__ float red[4][64];
  __shared__ float invs[64];
  int t = threadIdx.x, w4 = t >> 6, ln = t & 63;
  int b = blockIdx.y, n0 = blockIdx.x * 64;
  const float* xb = x + (size_t)b * C * N + n0;
  float ss = 0.f;
  #pragma unroll
  for (int it = 0; it < 64; ++it) {
    int c = it * 4 + w4;
    float v = xb[(size_t)c * N + ln];
    ss += v * v;
    xl[c][ln] = f2bf(v);
  }
  red[w4][ln] = ss;
  __syncthreads();
  if (t < 64) {
    float tot = red[0][t] + red[1][t] + red[2][t] + red[3][t];
    invs[t] = RMS_MUL / fmaxf(sqrtf(tot), EPS);
  }
  __syncthreads();
  float inv = invs[ln];
  ushort* dst = xbf + ((size_t)(b * N + n0 + ln)) * C + w4 * 64;
  #pragma unroll
  for (int ch = 0; ch < 8; ++ch) {
    union { ushort s[8]; uint4 v; } u;
    #pragma unroll
    for (int j = 0; j < 8; ++j)
      u.s[j] = f2bf(bf2f(xl[w4 * 64 + ch * 8 + j][ln]) * inv);
    *(uint4*)(dst + ch * 8) = u.v;
  }
}

// ---- GEMM1: y==0 -> q-softmax fused, bf16 out; y==1 -> kb; y==2 -> vb ----
__global__ __launch_bounds__(256) void k_gemm1(const ushort* __restrict__ A,
                                               const ushort* __restrict__ Bm,
                                               ushort* __restrict__ qb,
                                               ushort* __restrict__ kb,
                                               ushort* __restrict__ vb) {
  const int K = 256;
  __shared__ ushort Abuf[128 * 64];
  __shared__ ushort Bbuf[128 * 64];
  int t = threadIdx.x;
  int lane = t & 63, w = t >> 6;
  int wr = w >> 1, wc = w & 1;
  int n0 = blockIdx.x * 128, o0 = blockIdx.y * 128, b = blockIdx.z;
  const ushort* Ab = A + (size_t)o0 * K;
  const ushort* Bb = Bm + ((size_t)b * N + n0) * K;
  f32x4 acc[4][4] = {};
  for (int k0 = 0; k0 < K; k0 += 64) {
    #pragma unroll
    for (int i = 0; i < 4; ++i) {
      int chunk = w * 4 + i;
      int row = chunk * 8 + (lane >> 3);
      int col = k0 + (lane & 7) * 8;
      load_lds16(Ab + (size_t)row * K + col, Abuf + chunk * 512);
      load_lds16(Bb + (size_t)row * K + col, Bbuf + chunk * 512);
    }
    __syncthreads();
    #pragma unroll
    for (int kk = 0; kk < 2; ++kk) {
      short8 af[4], bfr[4];
      #pragma unroll
      for (int m = 0; m < 4; ++m)
        af[m] = *(const short8*)&Abuf[(wr * 64 + m * 16 + (lane & 15)) * 64 + kk * 32 + (lane >> 4) * 8];
      #pragma unroll
      for (int nn = 0; nn < 4; ++nn)
        bfr[nn] = *(const short8*)&Bbuf[(wc * 64 + nn * 16 + (lane & 15)) * 64 + kk * 32 + (lane >> 4) * 8];
      #pragma unroll
      for (int m = 0; m < 4; ++m)
        #pragma unroll
        for (int nn = 0; nn < 4; ++nn)
          acc[m][nn] = __builtin_amdgcn_mfma_f32_16x16x32_bf16(af[m], bfr[nn], acc[m][nn], 0, 0, 0);
    }
    __syncthreads();
  }
  if (blockIdx.y == 0) {
    // q-softmax over d=32 (rows wr*64 + hh*32 + [0,32)) per column, in-register.
    #pragma unroll
    for (int hh = 0; hh < 2; ++hh) {
      #pragma unroll
      for (int nn = 0; nn < 4; ++nn) {
        int m0 = hh * 2;
        float pm = -1e30f;
        #pragma unroll
        for (int mi = 0; mi < 2; ++mi)
          #pragma unroll
          for (int j = 0; j < 4; ++j) pm = fmaxf(pm, acc[m0 + mi][nn][j]);
        pm = fmaxf(pm, __shfl_xor(pm, 16));
        pm = fmaxf(pm, __shfl_xor(pm, 32));
        float e[2][4], ps = 0.f;
        #pragma unroll
        for (int mi = 0; mi < 2; ++mi)
          #pragma unroll
          for (int j = 0; j < 4; ++j) {
            e[mi][j] = __expf(acc[m0 + mi][nn][j] - pm);
            ps += e[mi][j];
          }
        ps += __shfl_xor(ps, 16);
        ps += __shfl_xor(ps, 32);
        float rs = QSCALE / ps;
        #pragma unroll
        for (int mi = 0; mi < 2; ++mi)
          #pragma unroll
          for (int j = 0; j < 4; ++j) acc[m0 + mi][nn][j] = e[mi][j] * rs;
      }
    }
  }
  ushort* dst = (blockIdx.y == 0) ? qb : (blockIdx.y == 1) ? kb : vb;
  ushort* Cb = dst + ((size_t)b * HID) * N + n0;
  #pragma unroll
  for (int m = 0; m < 4; ++m)
    #pragma unroll
    for (int nn = 0; nn < 4; ++nn)
      #pragma unroll
      for (int j = 0; j < 4; ++j) {
        int row = wr * 64 + m * 16 + (lane >> 4) * 4 + j;
        int col = wc * 64 + nn * 16 + (lane & 15);
        Cb[(size_t)row * N + col] = f2bf(acc[m][nn][j]);
      }
}

// ---- k row stats: kstat[r] = (max_n k, 1/sum_n exp(k-max)) over bf16 k ----
__global__ __launch_bounds__(256) void k_krowstat(const ushort* __restrict__ kb,
                                                  float2* __restrict__ kstat) {
  __shared__ float red[4];
  int r = blockIdx.x;                 // 0..2047
  int b = r >> 7, rem = r & 127;
  const ushort* row = kb + ((size_t)b * HID + rem) * N;
  int t = threadIdx.x;
  float v[16];
  float m = -1e30f;
  #pragma unroll
  for (int i = 0; i < 16; ++i) { v[i] = bf2f(row[i * 256 + t]); m = fmaxf(m, v[i]); }
  #pragma unroll
  for (int off = 32; off; off >>= 1) m = fmaxf(m, __shfl_xor(m, off));
  if ((t & 63) == 0) red[t >> 6] = m;
  __syncthreads();
  m = fmaxf(fmaxf(red[0], red[1]), fmaxf(red[2], red[3]));
  __syncthreads();
  float s = 0.f;
  #pragma unroll
  for (int i = 0; i < 16; ++i) s += __expf(v[i] - m);
  #pragma unroll
  for (int off = 32; off; off >>= 1) s += __shfl_xor(s, off);
  if ((t & 63) == 0) red[t >> 6] = s;
  __syncthreads();
  if (t == 0) {
    float tot = red[0] + red[1] + red[2] + red[3];
    kstat[r] = make_float2(m, 1.f / tot);
  }
}

// ---- split context with k-softmax folded into staging (bf16 k,v) ----
__global__ __launch_bounds__(256) void k_context(const ushort* __restrict__ kb,
                                                 const ushort* __restrict__ vb,
                                                 const float2* __restrict__ kstat,
                                                 float* __restrict__ ctxp) {
  __shared__ float kt[32 * 129];
  __shared__ float vt[32 * 129];
  __shared__ float km[32], krs[32];
  int s = blockIdx.x;
  int bh = blockIdx.y;
  int b = bh >> 2, h = bh & 3;
  int t = threadIdx.x;
  if (t < 32) {
    float2 st = kstat[bh * D + t];
    km[t] = st.x; krs[t] = st.y;
  }
  __syncthreads();
  int d = t >> 3, e0 = (t & 7) * 4;
  int n0 = s * 128;
  const ushort* kbase = kb + ((size_t)b * HID + h * D) * N;
  const ushort* vbase = vb + ((size_t)b * HID + h * D) * N;
  #pragma unroll
  for (int j = 0; j < 16; ++j) {
    int f = j * 256 + t;
    int row = f >> 7, col = f & 127;
    kt[row * 129 + col] = __expf(bf2f(kbase[(size_t)row * N + n0 + col]) - km[row]) * krs[row];
    vt[row * 129 + col] = bf2f(vbase[(size_t)row * N + n0 + col]);
  }
  __syncthreads();
  float acc[4] = {0.f, 0.f, 0.f, 0.f};
  for (int nn = 0; nn < 128; ++nn) {
    float kd = kt[d * 129 + nn];
    #pragma unroll
    for (int j = 0; j < 4; ++j) acc[j] += kd * vt[(e0 + j) * 129 + nn];
  }
  f32x4 v = {acc[0], acc[1], acc[2], acc[3]};
  *(f32x4*)(ctxp + ((size_t)(s * 64 + bh) * 1024) + d * 32 + e0) = v;
}

// ---- reduce partials: ctx[i] = sum_s ctxp[s][i] ----
__global__ __launch_bounds__(256) void k_redctx(const float* __restrict__ ctxp,
                                                float* __restrict__ ctx) {
  int idx = blockIdx.x * 256 + threadIdx.x;
  float s = 0.f;
  #pragma unroll
  for (int i = 0; i < NSPLIT; ++i) s += ctxp[(size_t)i * 65536 + idx];
  ctx[idx] = s;
}

// ---- out2bf[b][n][h*32+e] = bf16( sum_d ctx[b,h,d,e] * q[b,h,d,n] ) ----
__global__ __launch_bounds__(256) void k_out2(const ushort* __restrict__ qb,
                                              const float* __restrict__ ctx,
                                              ushort* __restrict__ out2bf) {
  __shared__ float cl[D * D];
  int t = threadIdx.x;
  int n = blockIdx.x * 256 + t;
  int bh = blockIdx.y;
  int b = bh >> 2, h = bh & 3;
  #pragma unroll
  for (int j = 0; j < 4; ++j) cl[j * 256 + t] = ctx[(size_t)bh * D * D + j * 256 + t];
  __syncthreads();
  float q[D];
  const ushort* qbb = qb + ((size_t)b * HID + h * D) * N + n;
  #pragma unroll
  for (int d = 0; d < D; ++d) q[d] = bf2f(qbb[(size_t)d * N]);
  float a[D];
  #pragma unroll
  for (int e = 0; e < D; ++e) {
    float s = 0.f;
    #pragma unroll
    for (int d = 0; d < D; ++d) s += cl[d * D + e] * q[d];
    a[e] = s;
  }
  ushort* ob = out2bf + ((size_t)(b * N + n)) * HID + h * D;
  #pragma unroll
  for (int g = 0; g < 4; ++g) {
    union { ushort s[8]; uint4 v; } u;
    #pragma unroll
    for (int j = 0; j < 8; ++j) u.s[j] = f2bf(a[g * 8 + j]);
    *(uint4*)(ob + g * 8) = u.v;
  }
}

// ---- GEMM2 (BM=256 full-M x BN=64) + bias + fused final rmsnorm ----
__global__ __launch_bounds__(256) void k_gemm2(const ushort* __restrict__ A,
                                               const ushort* __restrict__ Bm,
                                               const float* __restrict__ bias,
                                               const float* __restrict__ g,
                                               float* __restrict__ outp) {
  const int K = HID;                  // 128
  __shared__ ushort Abuf[256 * 64];   // 32 KB
  __shared__ ushort Bbuf[64 * 64];    // 8 KB
  __shared__ float ssred[4][64];
  __shared__ float biasl[C], gl[C];
  int t = threadIdx.x;
  int lane = t & 63, w = t >> 6;
  int n0 = blockIdx.x * 64, b = blockIdx.z;
  biasl[t] = bias[t];
  gl[t] = g[t];
  const ushort* Bb = Bm + ((size_t)b * N + n0) * K;
  f32x4 acc[4][4] = {};
  for (int k0 = 0; k0 < K; k0 += 64) {
    #pragma unroll
    for (int i = 0; i < 8; ++i) {
      int chunk = w * 8 + i;
      int row = chunk * 8 + (lane >> 3);
      int col = k0 + (lane & 7) * 8;
      load_lds16(A + (size_t)row * K + col, Abuf + chunk * 512);
    }
    #pragma unroll
    for (int i = 0; i < 2; ++i) {
      int chunk = w * 2 + i;
      int row = chunk * 8 + (lane >> 3);
      int col = k0 + (lane & 7) * 8;
      load_lds16(Bb + (size_t)row * K + col, Bbuf + chunk * 512);
    }
    __syncthreads();
    #pragma unroll
    for (int kk = 0; kk < 2; ++kk) {
      short8 af[4], bfr[4];
      #pragma unroll
      for (int m = 0; m < 4; ++m)
        af[m] = *(const short8*)&Abuf[(w * 64 + m * 16 + (lane & 15)) * 64 + kk * 32 + (lane >> 4) * 8];
      #pragma unroll
      for (int nn = 0; nn < 4; ++nn)
        bfr[nn] = *(const short8*)&Bbuf[(nn * 16 + (lane & 15)) * 64 + kk * 32 + (lane >> 4) * 8];
      #pragma unroll
      for (int m = 0; m < 4; ++m)
        #pragma unroll
        for (int nn = 0; nn < 4; ++nn)
          acc[m][nn] = __builtin_amdgcn_mfma_f32_16x16x32_bf16(af[m], bfr[nn], acc[m][nn], 0, 0, 0);
    }
    __syncthreads();
  }
  #pragma unroll
  for (int m = 0; m < 4; ++m)
    #pragma unroll
    for (int j = 0; j < 4; ++j) {
      int row = w * 64 + m * 16 + (lane >> 4) * 4 + j;
      float bv = biasl[row];
      #pragma unroll
      for (int nn = 0; nn < 4; ++nn) acc[m][nn][j] += bv;
    }
  float ssp[4];
  #pragma unroll
  for (int nn = 0; nn < 4; ++nn) {
    float s = 0.f;
    #pragma unroll
    for (int m = 0; m < 4; ++m)
      #pragma unroll
      for (int j = 0; j < 4; ++j) s += acc[m][nn][j] * acc[m][nn][j];
    s += __shfl_xor(s, 16);
    s += __shfl_xor(s, 32);
    ssp[nn] = s;
  }
  if ((lane >> 4) == 0) {
    #pragma unroll
    for (int nn = 0; nn < 4; ++nn) ssred[w][nn * 16 + (lane & 15)] = ssp[nn];
  }
  __syncthreads();
  float inv[4];
  #pragma unroll
  for (int nn = 0; nn < 4; ++nn) {
    int col = nn * 16 + (lane & 15);
    float tot = ssred[0][col] + ssred[1][col] + ssred[2][col] + ssred[3][col];
    inv[nn] = RMS_MUL / fmaxf(sqrtf(tot), EPS);
  }
  float* Cb = outp + (size_t)b * C * N + n0;
  #pragma unroll
  for (int m = 0; m < 4; ++m)
    #pragma unroll
    for (int j = 0; j < 4; ++j) {
      int row = w * 64 + m * 16 + (lane >> 4) * 4 + j;
      float gm = gl[row];
      #pragma unroll
      for (int nn = 0; nn < 4; ++nn) {
        int col = nn * 16 + (lane & 15);
        Cb[(size_t)row * N + col] = acc[m][nn][j] * inv[nn] * gm;
      }
    }
}

extern "C" void kernel_launch(void* const* d_in, const int* in_sizes, int n_in,
                              void* d_out, int out_size, void* d_ws, size_t ws_size,
                              hipStream_t stream) {
  const float* x    = (const float*)d_in[0];
  const float* gn   = (const float*)d_in[1];
  const float* wqkv = (const float*)d_in[2];
  const float* wout = (const float*)d_in[3];
  const float* bout = (const float*)d_in[4];
  const float* gout = (const float*)d_in[5];
  float* out = (float*)d_out;
  float* ws  = (float*)d_ws;

  ushort* xbf    = (ushort*)ws;                    // 16,777,216 bf16 (32 MB)
  ushort* qb     = (ushort*)(ws + 8388608);        //  8,388,608 bf16 (16 MB)
  ushort* kb     = (ushort*)(ws + 12582912);       // 16 MB
  ushort* vb     = (ushort*)(ws + 16777216);       // 16 MB
  ushort* out2bf = (ushort*)(ws + 20971520);       // 16 MB
  float*  ctxp   = ws + 25165824;                  //  8 MB
  float*  ctx    = ws + 27262976;                  // 256 KB
  float2* kstat  = (float2*)(ws + 27328512);       // 16 KB
  ushort* wA     = (ushort*)(ws + 27332608);       // 192 KB
  ushort* wB     = (ushort*)(ws + 27381760);       // 64 KB
  // total ~109.6 MB (< prior 134.7 MB footprint)

  k_prep_w  <<<512, 256, 0, stream>>>(wqkv, gn, wout, wA, wB);
  k_prep_x  <<<dim3(64, 16), 256, 0, stream>>>(x, xbf);
  k_gemm1   <<<dim3(32, 3, 16), 256, 0, stream>>>(wA, xbf, qb, kb, vb);
  k_krowstat<<<2048, 256, 0, stream>>>(kb, kstat);
  k_context <<<dim3(NSPLIT, 64), 256, 0, stream>>>(kb, vb, kstat, ctxp);
  k_redctx  <<<256, 256, 0, stream>>>(ctxp, ctx);
  k_out2    <<<dim3(16, 64), 256, 0, stream>>>(qb, ctx, out2bf);
  k_gemm2   <<<dim3(64, 1, 16), 256, 0, stream>>>(wB, out2bf, bout, gout, out);
}